// Round 8
// baseline (180.933 us; speedup 1.0000x reference)
//
#include <hip/hip_runtime.h>

typedef __bf16 bf16_t;
typedef unsigned short u16;
typedef __attribute__((ext_vector_type(8))) __bf16 bf16x8;
typedef __attribute__((ext_vector_type(4))) float f32x4;
typedef __attribute__((ext_vector_type(4))) u16 u16x4;
typedef __attribute__((ext_vector_type(8))) u16 u16x8;

#define SS 2048

__device__ __forceinline__ u16 f2b(float f) {
    return __builtin_bit_cast(u16, (__bf16)f);
}

// exp2 in ONE VALU op (v_exp_f32).
__device__ __forceinline__ float fexp2(float x) {
#if __has_builtin(__builtin_amdgcn_exp2f)
    return __builtin_amdgcn_exp2f(x);
#else
    float r;
    asm("v_exp_f32 %0, %1" : "=v"(r) : "v"(x));
    return r;
#endif
}

__device__ __forceinline__ void async_copy16(const u16* g, u16* l) {
    __builtin_amdgcn_global_load_lds(
        (__attribute__((address_space(1))) void*)(u16*)g,
        (__attribute__((address_space(3))) void*)l, 16, 0, 0);
}

__device__ __forceinline__ bf16x8 ldfrag(const u16* p) {
    return __builtin_bit_cast(bf16x8, *(const u16x8*)p);
}

// ------- fused transpose+cast of all 3 weights: src [1024][N] f32 -> dst [N][1024] bf16 -------
// z=0: Wq (scale = 0.125*log2e folded for exp2-domain softmax), z=1: Wkv, z=2: Wo
__global__ __launch_bounds__(256)
void transpose_all(const float* __restrict__ Wq, const float* __restrict__ Wkv,
                   const float* __restrict__ Wo, u16* __restrict__ WcatT,
                   u16* __restrict__ WoT) {
    const int z = blockIdx.z;
    if (z != 1 && blockIdx.y >= 16) return;
    const float* src; u16* dst; int N; float scale;
    if (z == 0)      { src = Wq;  dst = WcatT;               N = 1024; scale = 0.125f * 1.44269504089f; }
    else if (z == 1) { src = Wkv; dst = WcatT + 1024 * 1024; N = 2048; scale = 1.0f; }
    else             { src = Wo;  dst = WoT;                 N = 1024; scale = 1.0f; }
    __shared__ __attribute__((aligned(16))) u16 tile[64][72];
    const int k0 = blockIdx.x * 64, n0 = blockIdx.y * 64;
    const int tid = threadIdx.x;
#pragma unroll
    for (int p = 0; p < 4; ++p) {
        int c = p * 256 + tid;
        int r = c >> 4, c4 = c & 15;
        float4 v = *(const float4*)(src + (size_t)(k0 + r) * N + n0 + c4 * 4);
        u16x4 o;
        o[0] = f2b(v.x * scale); o[1] = f2b(v.y * scale);
        o[2] = f2b(v.z * scale); o[3] = f2b(v.w * scale);
        *(u16x4*)&tile[r][c4 * 4] = o;
    }
    __syncthreads();
#pragma unroll
    for (int p = 0; p < 4; ++p) {
        int c = p * 256 + tid;
        int n = c >> 4, k4 = c & 15;
        u16x4 o;
#pragma unroll
        for (int i = 0; i < 4; ++i) o[i] = tile[k4 * 4 + i][n];
        *(u16x4*)(dst + (size_t)(n0 + n) * 1024 + k0 + k4 * 4) = o;
    }
}

// ------- QKV GEMM: C[M,N] = cast_bf16(A_f32[M,K]) @ B[K,N], B given as BT[N,K]. -------
// R8: x's f32->bf16 cast FUSED into A-staging (cast_x kernel deleted; 16MB HBM
// round-trip + a launch saved). A-side is reg-staged with T14 split: issue 4x
// float4 loads for tile t+1 at iter-t top (whole compute phase as latency
// cover), cvt 16x f2b + 2x ds_write_b128 into the other buffer after compute.
// Identical numerics to the old cast_x (same f2b on same values).
// B-side global_load_lds dbuf, XCD-chunked grid, V-fused sigma^-1 epilogue
// (R7, kept): V tiles (n0>=2048) write straight to VT[bh][hd][s'].
__global__ __launch_bounds__(256, 3)
void gemm_qkv(const float* __restrict__ A, const u16* __restrict__ BT,
              u16* __restrict__ C, u16* __restrict__ VTg, int M, int N, int K) {
    __shared__ __attribute__((aligned(16))) u16 As[2][128 * 32];
    __shared__ __attribute__((aligned(16))) u16 Bs[2][128 * 32];
    const int tid = threadIdx.x;
    const int wave = tid >> 6, lane = tid & 63;
    const int l15 = lane & 15, quad = lane >> 4;
    // XCD-chunked decode: XCD k (wid%8) owns logical tiles [k*per, (k+1)*per)
    const int wid = blockIdx.x;
    const int per = (int)(gridDim.x >> 3);
    const int logical = (wid & 7) * per + (wid >> 3);
    const int nxt = N >> 7;
    const int ty = logical / nxt, tx = logical - ty * nxt;
    const int m0 = ty * 128, n0 = tx * 128;
    const int wm = (wave >> 1) * 64, wn = (wave & 1) * 64;
    const f32x4 zero = {0.f, 0.f, 0.f, 0.f};
    f32x4 acc[4][4];
#pragma unroll
    for (int i = 0; i < 4; ++i)
#pragma unroll
        for (int j = 0; j < 4; ++j) acc[i][j] = zero;
    const int r0 = tid >> 2, kc = (tid & 3) * 8;
    const int arow = tid >> 1, ak = (tid & 1) * 16;  // A: own row, k-half
    const float* abase = A + (size_t)(m0 + arow) * K + ak;
    float4 a_reg[4];
    auto loadA = [&](int k0) {
        const float* src = abase + k0;
        a_reg[0] = *(const float4*)(src);
        a_reg[1] = *(const float4*)(src + 4);
        a_reg[2] = *(const float4*)(src + 8);
        a_reg[3] = *(const float4*)(src + 12);
    };
    auto writeA = [&](int bsel) {  // cvt + 2x ds_write_b128 (lane-contiguous 32B)
        u16x8 o0, o1;
#pragma unroll
        for (int i = 0; i < 4; ++i) {
            o0[i]     = f2b(a_reg[0][i]); o0[4 + i] = f2b(a_reg[1][i]);
            o1[i]     = f2b(a_reg[2][i]); o1[4 + i] = f2b(a_reg[3][i]);
        }
        *(u16x8*)(As[bsel] + arow * 32 + ak)     = o0;
        *(u16x8*)(As[bsel] + arow * 32 + ak + 8) = o1;
    };
    auto stageB = [&](int bsel, int k0) {
        async_copy16(BT + (size_t)(n0 + r0) * K + k0 + kc, Bs[bsel] + tid * 8);
        async_copy16(BT + (size_t)(n0 + 64 + r0) * K + k0 + kc, Bs[bsel] + (256 + tid) * 8);
    };
    loadA(0);
    stageB(0, 0);
    writeA(0);
    __syncthreads();
    const int nk = K >> 5;
    for (int t = 0; t < nk; ++t) {
        if (t + 1 < nk) {  // issue next-tile loads; in flight across this compute
            loadA((t + 1) * 32);
            stageB((t + 1) & 1, (t + 1) * 32);
        }
        const u16* Ab = As[t & 1];
        const u16* Bb = Bs[t & 1];
        bf16x8 af[4], bf[4];
#pragma unroll
        for (int s = 0; s < 4; ++s) {
            af[s] = ldfrag(Ab + (wm + s * 16 + l15) * 32 + quad * 8);
            bf[s] = ldfrag(Bb + (wn + s * 16 + l15) * 32 + quad * 8);
        }
#pragma unroll
        for (int mt = 0; mt < 4; ++mt)
#pragma unroll
            for (int nt = 0; nt < 4; ++nt)
                acc[mt][nt] = __builtin_amdgcn_mfma_f32_16x16x32_bf16(
                    af[mt], bf[nt], acc[mt][nt], 0, 0, 0);
        if (t + 1 < nk) writeA((t + 1) & 1);  // vmcnt-waits a_reg; other buffer
        __syncthreads();  // drains B asyncs + A ds_writes; LDS reads done
    }
    if (n0 >= 2048) {
        // V tile -> VT[bh][hd][s'] directly (sigma^-1), skip QKV C-write.
#pragma unroll
        for (int mt = 0; mt < 4; ++mt)
#pragma unroll
            for (int nt = 0; nt < 4; ++nt) {
                const int n_g = n0 + wn + nt * 16 + l15 - 2048;
                const int hd = n_g & 63, h = n_g >> 6;
                const int m_g = m0 + wm + mt * 16 + quad * 4;
                const int bb = m_g >> 11;
                const int s = m_g & 2047;
                const int sb = s & 63;
                const int col = (sb & 32) | ((sb & 12) << 1) | ((sb >> 2) & 4);
                u16x4 o;
#pragma unroll
                for (int r = 0; r < 4; ++r) o[r] = f2b(acc[mt][nt][r]);
                *(u16x4*)(VTg + ((size_t)(bb * 16 + h) * 64 + hd) * 2048
                          + (s & ~63) + col) = o;
            }
        return;
    }
#pragma unroll
    for (int mt = 0; mt < 4; ++mt)
#pragma unroll
        for (int nt = 0; nt < 4; ++nt) {
            const int n = n0 + wn + nt * 16 + l15;
#pragma unroll
            for (int r = 0; r < 4; ++r) {
                const int m = m0 + wm + mt * 16 + quad * 4 + r;
                C[(size_t)m * N + n] = f2b(acc[mt][nt][r]);
            }
        }
}

// ------- GEMM variant: 128x64 tile (for N=1024 out-proj). dbuf + XCD chunking. -------
__global__ __launch_bounds__(256, 2)
void gemm_bt64(const u16* __restrict__ A, const u16* __restrict__ BT,
               float* __restrict__ C, int M, int N, int K) {
    __shared__ __attribute__((aligned(16))) u16 As[2][128 * 32];
    __shared__ __attribute__((aligned(16))) u16 Bs[2][64 * 32];
    const int tid = threadIdx.x;
    const int wave = tid >> 6, lane = tid & 63;
    const int l15 = lane & 15, quad = lane >> 4;
    const int wid = blockIdx.x;
    const int per = (int)(gridDim.x >> 3);
    const int logical = (wid & 7) * per + (wid >> 3);
    const int nxt = N >> 6;
    const int ty = logical / nxt, tx = logical - ty * nxt;
    const int m0 = ty * 128, n0 = tx * 64;
    const int wm = (wave >> 1) * 64, wn = (wave & 1) * 32;
    const f32x4 zero = {0.f, 0.f, 0.f, 0.f};
    f32x4 acc[4][2];
#pragma unroll
    for (int i = 0; i < 4; ++i)
#pragma unroll
        for (int j = 0; j < 2; ++j) acc[i][j] = zero;
    const int r0 = tid >> 2, kc = (tid & 3) * 8;
    auto stage = [&](int bsel, int k0) {
        async_copy16(A + (size_t)(m0 + r0) * K + k0 + kc, As[bsel] + tid * 8);
        async_copy16(A + (size_t)(m0 + 64 + r0) * K + k0 + kc, As[bsel] + (256 + tid) * 8);
        async_copy16(BT + (size_t)(n0 + r0) * K + k0 + kc, Bs[bsel] + tid * 8);
    };
    stage(0, 0);
    __syncthreads();
    const int nk = K >> 5;
    for (int t = 0; t < nk; ++t) {
        if (t + 1 < nk) stage((t + 1) & 1, (t + 1) * 32);
        const u16* Ab = As[t & 1];
        const u16* Bb = Bs[t & 1];
        bf16x8 af[4], bf[2];
#pragma unroll
        for (int s = 0; s < 4; ++s)
            af[s] = ldfrag(Ab + (wm + s * 16 + l15) * 32 + quad * 8);
#pragma unroll
        for (int s = 0; s < 2; ++s)
            bf[s] = ldfrag(Bb + (wn + s * 16 + l15) * 32 + quad * 8);
#pragma unroll
        for (int mt = 0; mt < 4; ++mt)
#pragma unroll
            for (int nt = 0; nt < 2; ++nt)
                acc[mt][nt] = __builtin_amdgcn_mfma_f32_16x16x32_bf16(
                    af[mt], bf[nt], acc[mt][nt], 0, 0, 0);
        __syncthreads();
    }
#pragma unroll
    for (int mt = 0; mt < 4; ++mt)
#pragma unroll
        for (int nt = 0; nt < 2; ++nt) {
            const int n = n0 + wn + nt * 16 + l15;
#pragma unroll
            for (int r = 0; r < 4; ++r) {
                const int m = m0 + wm + mt * 16 + quad * 4 + r;
                C[(size_t)m * N + n] = acc[mt][nt][r];
            }
        }
}

// ------- flash attention, causal, fixed-shift softmax, P-in-registers. -------
// R6 winner, UNCHANGED: dual-tile, KVBLK=64, XCD-chunked pair-balanced grid.
__global__ __launch_bounds__(256, 2)
void attn_kernel(const u16* __restrict__ QKV, const u16* __restrict__ VTg,
                 u16* __restrict__ AO) {
    __shared__ __attribute__((aligned(16))) u16 Kt[2][2 * 64 * 32];
    __shared__ __attribute__((aligned(16))) u16 Vt[2][2 * 64 * 32];
    const int tid = threadIdx.x;
    const int wave = tid >> 6, lane = tid & 63;
    const int l15 = lane & 15, quad = lane >> 4;
    const int w16 = wave * 16;
    // XCD-chunked, pair-balanced decode (512 blocks, 64 per XCD)
    const int wid = blockIdx.x;
    const int g = wid >> 3;                 // 0..63 slot within this XCD
    const int jj = g & 15, hf = jj >> 1;
    const int xe0 = (jj & 1) ? 15 - hf : hf;   // 0,15,1,14,...
    const int xe = (g & 32) ? 15 - xe0 : xe0;  // mirrored upper half
    const int bh = (wid & 7) * 4 + (g >> 4);   // 4 bh per XCD
    const int b = bh >> 4, h = bh & 15;
    const int qbA = 31 - xe, qbB = xe;
    const int qA0 = qbA * 64, qB0 = qbB * 64;
    const size_t bS = (size_t)b * SS;
    const u16* vbase = VTg + (size_t)bh * 64 * 2048;
    const int rr = (tid >> 2) & 63, kc8 = (tid & 3) * 8;

    // stage kv block 0
    {
        const u16* ksrc = QKV + (bS + rr) * 3072 + 1024 + h * 64 + kc8;
        async_copy16(ksrc,      Kt[0] + tid * 8);
        async_copy16(ksrc + 32, Kt[0] + (256 + tid) * 8);
        const u16* vsrc = vbase + (size_t)rr * 2048 + kc8;
        async_copy16(vsrc,      Vt[0] + tid * 8);
        async_copy16(vsrc + 32, Vt[0] + (256 + tid) * 8);
    }
    // Q direct global->reg: wave's own 16 q-rows per tile
    bf16x8 qfA[2], qfB[2];
    {
        const u16* qA = QKV + (bS + qA0 + w16 + l15) * 3072 + h * 64 + quad * 8;
        qfA[0] = ldfrag(qA); qfA[1] = ldfrag(qA + 32);
        const u16* qB = QKV + (bS + qB0 + w16 + l15) * 3072 + h * 64 + quad * 8;
        qfB[0] = ldfrag(qB); qfB[1] = ldfrag(qB + 32);
    }
    float lA = 0.f, lB = 0.f;
    f32x4 OA[4], OB[4];
    const f32x4 zero = {0.f, 0.f, 0.f, 0.f};
#pragma unroll
    for (int nt = 0; nt < 4; ++nt) { OA[nt] = zero; OB[nt] = zero; }
    const f32x4 cinit = {-10.f, -10.f, -10.f, -10.f};  // folded softmax shift
    __syncthreads();  // kv block 0 staged

    for (int j = 0; j <= qbA; ++j) {
        if (j < qbA) {  // prefetch j+1; drained by end-of-iter barrier (full cover)
            const int kv1 = (j + 1) * 64;
            const int nb = (j + 1) & 1;
            const u16* ksrc = QKV + (bS + kv1 + rr) * 3072 + 1024 + h * 64 + kc8;
            async_copy16(ksrc,      Kt[nb] + tid * 8);
            async_copy16(ksrc + 32, Kt[nb] + (256 + tid) * 8);
            const u16* vsrc = vbase + (size_t)rr * 2048 + kv1 + kc8;
            async_copy16(vsrc,      Vt[nb] + tid * 8);
            async_copy16(vsrc + 32, Vt[nb] + (256 + tid) * 8);
        }
        const bool bAct = (j <= qbB);  // block-uniform
        const bool dA = (j == qbA), dB = (j == qbB);
        const u16* KB = Kt[j & 1];
        const u16* VB = Vt[j & 1];
        bf16x8 vf[4][2];
#pragma unroll
        for (int nt = 0; nt < 4; ++nt)
#pragma unroll
            for (int ks = 0; ks < 2; ++ks)
                vf[nt][ks] = ldfrag(VB + ks * 2048 + (nt * 16 + l15) * 32 + quad * 8);
        // S^T over all 4 kv-subtiles for this wave's q-rows; P stays in regs.
        u16x4 pcA[4], pcB[4];
#pragma unroll
        for (int c = 0; c < 4; ++c) {
            bf16x8 kf0 = ldfrag(KB + (c * 16 + l15) * 32 + quad * 8);
            bf16x8 kf1 = ldfrag(KB + 2048 + (c * 16 + l15) * 32 + quad * 8);
            f32x4 a = __builtin_amdgcn_mfma_f32_16x16x32_bf16(kf0, qfA[0], cinit, 0, 0, 0);
            f32x4 s = __builtin_amdgcn_mfma_f32_16x16x32_bf16(kf1, qfA[1], a, 0, 0, 0);
            if (dA) {  // mask iff local kv > local q
#pragma unroll
                for (int r = 0; r < 4; ++r)
                    if (c * 16 + quad * 4 + r > w16 + l15) s[r] = -1e30f;
            }
            u16x4 pk; float acc = 0.f;
#pragma unroll
            for (int r = 0; r < 4; ++r) {
                float pv = fexp2(s[r]);
                acc += pv;
                pk[r] = f2b(pv);
            }
            lA += acc; pcA[c] = pk;
            if (bAct) {
                f32x4 a2 = __builtin_amdgcn_mfma_f32_16x16x32_bf16(kf0, qfB[0], cinit, 0, 0, 0);
                f32x4 s2 = __builtin_amdgcn_mfma_f32_16x16x32_bf16(kf1, qfB[1], a2, 0, 0, 0);
                if (dB) {
#pragma unroll
                    for (int r = 0; r < 4; ++r)
                        if (c * 16 + quad * 4 + r > w16 + l15) s2[r] = -1e30f;
                }
                u16x4 pk2; float acc2 = 0.f;
#pragma unroll
                for (int r = 0; r < 4; ++r) {
                    float pv = fexp2(s2[r]);
                    acc2 += pv;
                    pk2[r] = f2b(pv);
                }
                lB += acc2; pcB[c] = pk2;
            }
        }
        // PV: A-frag = own registers in (c,r) order, matching sigma-permuted V.
        bf16x8 paA[2], paB[2];
#pragma unroll
        for (int ks = 0; ks < 2; ++ks) {
            u16x8 t;
#pragma unroll
            for (int i = 0; i < 4; ++i) { t[i] = pcA[2 * ks][i]; t[4 + i] = pcA[2 * ks + 1][i]; }
            paA[ks] = __builtin_bit_cast(bf16x8, t);
        }
#pragma unroll
        for (int nt = 0; nt < 4; ++nt) {
            OA[nt] = __builtin_amdgcn_mfma_f32_16x16x32_bf16(paA[0], vf[nt][0], OA[nt], 0, 0, 0);
            OA[nt] = __builtin_amdgcn_mfma_f32_16x16x32_bf16(paA[1], vf[nt][1], OA[nt], 0, 0, 0);
        }
        if (bAct) {
#pragma unroll
            for (int ks = 0; ks < 2; ++ks) {
                u16x8 t;
#pragma unroll
                for (int i = 0; i < 4; ++i) { t[i] = pcB[2 * ks][i]; t[4 + i] = pcB[2 * ks + 1][i]; }
                paB[ks] = __builtin_bit_cast(bf16x8, t);
            }
#pragma unroll
            for (int nt = 0; nt < 4; ++nt) {
                OB[nt] = __builtin_amdgcn_mfma_f32_16x16x32_bf16(paB[0], vf[nt][0], OB[nt], 0, 0, 0);
                OB[nt] = __builtin_amdgcn_mfma_f32_16x16x32_bf16(paB[1], vf[nt][1], OB[nt], 0, 0, 0);
            }
        }
        __syncthreads();  // reads done + prefetch j+1 landed
    }

    // epilogue: all-shuffle. l partial per lane; xor16+xor32 sums the quads.
    lA += __shfl_xor(lA, 16); lA += __shfl_xor(lA, 32);
    lB += __shfl_xor(lB, 16); lB += __shfl_xor(lB, 32);
#pragma unroll
    for (int r = 0; r < 4; ++r) {
        const int ql = quad * 4 + r;   // local q row of O (D layout: row=quad*4+r)
        float invA = 1.0f / __shfl(lA, ql);
        float invB = 1.0f / __shfl(lB, ql);
        size_t rowA = bS + (size_t)qA0 + w16 + ql;
        size_t rowB = bS + (size_t)qB0 + w16 + ql;
#pragma unroll
        for (int nt = 0; nt < 4; ++nt) {
            AO[rowA * 1024 + h * 64 + nt * 16 + l15] = f2b(OA[nt][r] * invA);
            AO[rowB * 1024 + h * 64 + nt * 16 + l15] = f2b(OB[nt][r] * invB);
        }
    }
}

extern "C" void kernel_launch(void* const* d_in, const int* in_sizes, int n_in,
                              void* d_out, int out_size, void* d_ws, size_t ws_size,
                              hipStream_t stream) {
    (void)in_sizes; (void)n_in; (void)out_size; (void)ws_size;
    const float* x   = (const float*)d_in[0];
    const float* Wq  = (const float*)d_in[1];
    const float* Wkv = (const float*)d_in[2];
    const float* Wo  = (const float*)d_in[3];
    float* out = (float*)d_out;
    char* ws = (char*)d_ws;
    u16* AO    = (u16*)(ws);                      // 8 MB   attn out bf16 [4096][1024]
    u16* WcatT = (u16*)(ws + (size_t)(8 << 20));  // 6 MB   [Wq*s | Wkv]^T  [3072][1024]
    u16* WoT   = (u16*)(ws + (size_t)(14 << 20)); // 2 MB   Wo^T [1024][1024]
    u16* QKV   = (u16*)(ws + (size_t)(16 << 20)); // 24 MB  [4096][3072] (V cols unused)
    u16* VTb   = (u16*)(ws + (size_t)(40 << 20)); // 8 MB   [32][64][2048] sigma-permuted

    transpose_all<<<dim3(16, 32, 3), 256, 0, stream>>>(Wq, Wkv, Wo, WcatT, WoT);
    gemm_qkv<<<768, 256, 0, stream>>>(x, WcatT, QKV, VTb, 4096, 3072, 1024);
    attn_kernel<<<512, 256, 0, stream>>>(QKV, VTb, AO);
    gemm_bt64<<<512, 256, 0, stream>>>(AO, WoT, out, 4096, 1024, 1024);
}

// Round 9
// 170.331 us; speedup vs baseline: 1.0622x; 1.0622x over previous
//
#include <hip/hip_runtime.h>

typedef __bf16 bf16_t;
typedef unsigned short u16;
typedef __attribute__((ext_vector_type(8))) __bf16 bf16x8;
typedef __attribute__((ext_vector_type(4))) float f32x4;
typedef __attribute__((ext_vector_type(4))) u16 u16x4;
typedef __attribute__((ext_vector_type(8))) u16 u16x8;

#define SS 2048

__device__ __forceinline__ u16 f2b(float f) {
    return __builtin_bit_cast(u16, (__bf16)f);
}

// exp2 in ONE VALU op (v_exp_f32).
__device__ __forceinline__ float fexp2(float x) {
#if __has_builtin(__builtin_amdgcn_exp2f)
    return __builtin_amdgcn_exp2f(x);
#else
    float r;
    asm("v_exp_f32 %0, %1" : "=v"(r) : "v"(x));
    return r;
#endif
}

__device__ __forceinline__ void async_copy16(const u16* g, u16* l) {
    __builtin_amdgcn_global_load_lds(
        (__attribute__((address_space(1))) void*)(u16*)g,
        (__attribute__((address_space(3))) void*)l, 16, 0, 0);
}

__device__ __forceinline__ bf16x8 ldfrag(const u16* p) {
    return __builtin_bit_cast(bf16x8, *(const u16x8*)p);
}

// ---------------- cast x: f32 -> bf16 ----------------
// R9: RESTORED. R8's cast-fusion into the GEMM A-staging was net-negative
// (gemm 43->56.5us: vmcnt+cvt+4-way-conflicted ds_write on the K-loop critical
// path, f32 A bytes doubled, T14's compute-cover prerequisite violated).
// The 24MB round-trip through a dedicated memory-bound kernel is CHEAPER.
__global__ __launch_bounds__(256)
void cast_x_kernel(const float* __restrict__ x, u16* __restrict__ xb) {
    size_t i = ((size_t)blockIdx.x * 256 + threadIdx.x) * 8;
    float4 a = *(const float4*)(x + i);
    float4 b = *(const float4*)(x + i + 4);
    u16x8 o;
    o[0] = f2b(a.x); o[1] = f2b(a.y); o[2] = f2b(a.z); o[3] = f2b(a.w);
    o[4] = f2b(b.x); o[5] = f2b(b.y); o[6] = f2b(b.z); o[7] = f2b(b.w);
    *(u16x8*)(xb + i) = o;
}

// ------- fused transpose+cast of all 3 weights: src [1024][N] f32 -> dst [N][1024] bf16 -------
// z=0: Wq (scale = 0.125*log2e folded for exp2-domain softmax), z=1: Wkv, z=2: Wo
__global__ __launch_bounds__(256)
void transpose_all(const float* __restrict__ Wq, const float* __restrict__ Wkv,
                   const float* __restrict__ Wo, u16* __restrict__ WcatT,
                   u16* __restrict__ WoT) {
    const int z = blockIdx.z;
    if (z != 1 && blockIdx.y >= 16) return;
    const float* src; u16* dst; int N; float scale;
    if (z == 0)      { src = Wq;  dst = WcatT;               N = 1024; scale = 0.125f * 1.44269504089f; }
    else if (z == 1) { src = Wkv; dst = WcatT + 1024 * 1024; N = 2048; scale = 1.0f; }
    else             { src = Wo;  dst = WoT;                 N = 1024; scale = 1.0f; }
    __shared__ __attribute__((aligned(16))) u16 tile[64][72];
    const int k0 = blockIdx.x * 64, n0 = blockIdx.y * 64;
    const int tid = threadIdx.x;
#pragma unroll
    for (int p = 0; p < 4; ++p) {
        int c = p * 256 + tid;
        int r = c >> 4, c4 = c & 15;
        float4 v = *(const float4*)(src + (size_t)(k0 + r) * N + n0 + c4 * 4);
        u16x4 o;
        o[0] = f2b(v.x * scale); o[1] = f2b(v.y * scale);
        o[2] = f2b(v.z * scale); o[3] = f2b(v.w * scale);
        *(u16x4*)&tile[r][c4 * 4] = o;
    }
    __syncthreads();
#pragma unroll
    for (int p = 0; p < 4; ++p) {
        int c = p * 256 + tid;
        int n = c >> 4, k4 = c & 15;
        u16x4 o;
#pragma unroll
        for (int i = 0; i < 4; ++i) o[i] = tile[k4 * 4 + i][n];
        *(u16x4*)(dst + (size_t)(n0 + n) * 1024 + k0 + k4 * 4) = o;
    }
}

// ------- GEMM: C[M,N] = A[M,K] @ B[K,N], B given transposed BT[N,K]. bf16 MFMA -------
// dbuf T3-minimum schedule (R2: neutral; kept). R6: XCD-chunked 1-D grid (kept).
// R7: V-FUSED EPILOGUE (kept; proven -6.5us). For n0 >= 2048 (V tiles) the tile
// is written DIRECTLY to VT[bh][hd][s'] sigma^-1-permuted, QKV C-write skipped.
// col = (sb&32)|((sb&12)<<1)|((sb>>2)&4), sb = s&63 (4-aligned).
template <typename OutT>
__global__ __launch_bounds__(256, 3)
void gemm_bt(const u16* __restrict__ A, const u16* __restrict__ BT,
             OutT* __restrict__ C, u16* __restrict__ VTg, int M, int N, int K) {
    __shared__ __attribute__((aligned(16))) u16 As[2][128 * 32];
    __shared__ __attribute__((aligned(16))) u16 Bs[2][128 * 32];
    const int tid = threadIdx.x;
    const int wave = tid >> 6, lane = tid & 63;
    const int l15 = lane & 15, quad = lane >> 4;
    // XCD-chunked decode: XCD k (wid%8) owns logical tiles [k*per, (k+1)*per)
    const int wid = blockIdx.x;
    const int per = (int)(gridDim.x >> 3);
    const int logical = (wid & 7) * per + (wid >> 3);
    const int nxt = N >> 7;
    const int ty = logical / nxt, tx = logical - ty * nxt;
    const int m0 = ty * 128, n0 = tx * 128;
    const int wm = (wave >> 1) * 64, wn = (wave & 1) * 64;
    const f32x4 zero = {0.f, 0.f, 0.f, 0.f};
    f32x4 acc[4][4];
#pragma unroll
    for (int i = 0; i < 4; ++i)
#pragma unroll
        for (int j = 0; j < 4; ++j) acc[i][j] = zero;
    const int r0 = tid >> 2, kc = (tid & 3) * 8;
    auto stage = [&](int bsel, int k0) {
        async_copy16(A + (size_t)(m0 + r0) * K + k0 + kc, As[bsel] + tid * 8);
        async_copy16(BT + (size_t)(n0 + r0) * K + k0 + kc, Bs[bsel] + tid * 8);
        async_copy16(A + (size_t)(m0 + 64 + r0) * K + k0 + kc, As[bsel] + (256 + tid) * 8);
        async_copy16(BT + (size_t)(n0 + 64 + r0) * K + k0 + kc, Bs[bsel] + (256 + tid) * 8);
    };
    stage(0, 0);
    __syncthreads();
    const int nk = K >> 5;
    for (int t = 0; t < nk; ++t) {
        if (t + 1 < nk) stage((t + 1) & 1, (t + 1) * 32);
        const u16* Ab = As[t & 1];
        const u16* Bb = Bs[t & 1];
        bf16x8 af[4], bf[4];
#pragma unroll
        for (int s = 0; s < 4; ++s) {
            af[s] = ldfrag(Ab + (wm + s * 16 + l15) * 32 + quad * 8);
            bf[s] = ldfrag(Bb + (wn + s * 16 + l15) * 32 + quad * 8);
        }
#pragma unroll
        for (int mt = 0; mt < 4; ++mt)
#pragma unroll
            for (int nt = 0; nt < 4; ++nt)
                acc[mt][nt] = __builtin_amdgcn_mfma_f32_16x16x32_bf16(
                    af[mt], bf[nt], acc[mt][nt], 0, 0, 0);
        __syncthreads();
    }
    if constexpr (sizeof(OutT) == 2) {
        if (n0 >= 2048) {
            // V tile -> VT[bh][hd][s'] directly (sigma^-1), skip QKV C-write.
#pragma unroll
            for (int mt = 0; mt < 4; ++mt)
#pragma unroll
                for (int nt = 0; nt < 4; ++nt) {
                    const int n_g = n0 + wn + nt * 16 + l15 - 2048;
                    const int hd = n_g & 63, h = n_g >> 6;
                    const int m_g = m0 + wm + mt * 16 + quad * 4;
                    const int bb = m_g >> 11;
                    const int s = m_g & 2047;
                    const int sb = s & 63;
                    const int col = (sb & 32) | ((sb & 12) << 1) | ((sb >> 2) & 4);
                    u16x4 o;
#pragma unroll
                    for (int r = 0; r < 4; ++r) o[r] = f2b(acc[mt][nt][r]);
                    *(u16x4*)(VTg + ((size_t)(bb * 16 + h) * 64 + hd) * 2048
                              + (s & ~63) + col) = o;
                }
            return;
        }
    }
#pragma unroll
    for (int mt = 0; mt < 4; ++mt)
#pragma unroll
        for (int nt = 0; nt < 4; ++nt) {
            const int n = n0 + wn + nt * 16 + l15;
#pragma unroll
            for (int r = 0; r < 4; ++r) {
                const int m = m0 + wm + mt * 16 + quad * 4 + r;
                float v = acc[mt][nt][r];
                if constexpr (sizeof(OutT) == 2) C[(size_t)m * N + n] = (OutT)f2b(v);
                else                             C[(size_t)m * N + n] = v;
            }
        }
}

// ------- GEMM variant: 128x64 tile (for N=1024 out-proj). dbuf + XCD chunking. -------
__global__ __launch_bounds__(256, 2)
void gemm_bt64(const u16* __restrict__ A, const u16* __restrict__ BT,
               float* __restrict__ C, int M, int N, int K) {
    __shared__ __attribute__((aligned(16))) u16 As[2][128 * 32];
    __shared__ __attribute__((aligned(16))) u16 Bs[2][64 * 32];
    const int tid = threadIdx.x;
    const int wave = tid >> 6, lane = tid & 63;
    const int l15 = lane & 15, quad = lane >> 4;
    const int wid = blockIdx.x;
    const int per = (int)(gridDim.x >> 3);
    const int logical = (wid & 7) * per + (wid >> 3);
    const int nxt = N >> 6;
    const int ty = logical / nxt, tx = logical - ty * nxt;
    const int m0 = ty * 128, n0 = tx * 64;
    const int wm = (wave >> 1) * 64, wn = (wave & 1) * 32;
    const f32x4 zero = {0.f, 0.f, 0.f, 0.f};
    f32x4 acc[4][2];
#pragma unroll
    for (int i = 0; i < 4; ++i)
#pragma unroll
        for (int j = 0; j < 2; ++j) acc[i][j] = zero;
    const int r0 = tid >> 2, kc = (tid & 3) * 8;
    auto stage = [&](int bsel, int k0) {
        async_copy16(A + (size_t)(m0 + r0) * K + k0 + kc, As[bsel] + tid * 8);
        async_copy16(A + (size_t)(m0 + 64 + r0) * K + k0 + kc, As[bsel] + (256 + tid) * 8);
        async_copy16(BT + (size_t)(n0 + r0) * K + k0 + kc, Bs[bsel] + tid * 8);
    };
    stage(0, 0);
    __syncthreads();
    const int nk = K >> 5;
    for (int t = 0; t < nk; ++t) {
        if (t + 1 < nk) stage((t + 1) & 1, (t + 1) * 32);
        const u16* Ab = As[t & 1];
        const u16* Bb = Bs[t & 1];
        bf16x8 af[4], bf[2];
#pragma unroll
        for (int s = 0; s < 4; ++s)
            af[s] = ldfrag(Ab + (wm + s * 16 + l15) * 32 + quad * 8);
#pragma unroll
        for (int s = 0; s < 2; ++s)
            bf[s] = ldfrag(Bb + (wn + s * 16 + l15) * 32 + quad * 8);
#pragma unroll
        for (int mt = 0; mt < 4; ++mt)
#pragma unroll
            for (int nt = 0; nt < 2; ++nt)
                acc[mt][nt] = __builtin_amdgcn_mfma_f32_16x16x32_bf16(
                    af[mt], bf[nt], acc[mt][nt], 0, 0, 0);
        __syncthreads();
    }
#pragma unroll
    for (int mt = 0; mt < 4; ++mt)
#pragma unroll
        for (int nt = 0; nt < 2; ++nt) {
            const int n = n0 + wn + nt * 16 + l15;
#pragma unroll
            for (int r = 0; r < 4; ++r) {
                const int m = m0 + wm + mt * 16 + quad * 4 + r;
                C[(size_t)m * N + n] = acc[mt][nt][r];
            }
        }
}

// ------- flash attention, causal, fixed-shift softmax, P-in-registers. -------
// R6 winner, UNCHANGED: dual-tile, KVBLK=64, XCD-chunked pair-balanced grid.
__global__ __launch_bounds__(256, 2)
void attn_kernel(const u16* __restrict__ QKV, const u16* __restrict__ VTg,
                 u16* __restrict__ AO) {
    __shared__ __attribute__((aligned(16))) u16 Kt[2][2 * 64 * 32];
    __shared__ __attribute__((aligned(16))) u16 Vt[2][2 * 64 * 32];
    const int tid = threadIdx.x;
    const int wave = tid >> 6, lane = tid & 63;
    const int l15 = lane & 15, quad = lane >> 4;
    const int w16 = wave * 16;
    // XCD-chunked, pair-balanced decode (512 blocks, 64 per XCD)
    const int wid = blockIdx.x;
    const int g = wid >> 3;                 // 0..63 slot within this XCD
    const int jj = g & 15, hf = jj >> 1;
    const int xe0 = (jj & 1) ? 15 - hf : hf;   // 0,15,1,14,...
    const int xe = (g & 32) ? 15 - xe0 : xe0;  // mirrored upper half
    const int bh = (wid & 7) * 4 + (g >> 4);   // 4 bh per XCD
    const int b = bh >> 4, h = bh & 15;
    const int qbA = 31 - xe, qbB = xe;
    const int qA0 = qbA * 64, qB0 = qbB * 64;
    const size_t bS = (size_t)b * SS;
    const u16* vbase = VTg + (size_t)bh * 64 * 2048;
    const int rr = (tid >> 2) & 63, kc8 = (tid & 3) * 8;

    // stage kv block 0
    {
        const u16* ksrc = QKV + (bS + rr) * 3072 + 1024 + h * 64 + kc8;
        async_copy16(ksrc,      Kt[0] + tid * 8);
        async_copy16(ksrc + 32, Kt[0] + (256 + tid) * 8);
        const u16* vsrc = vbase + (size_t)rr * 2048 + kc8;
        async_copy16(vsrc,      Vt[0] + tid * 8);
        async_copy16(vsrc + 32, Vt[0] + (256 + tid) * 8);
    }
    // Q direct global->reg: wave's own 16 q-rows per tile
    bf16x8 qfA[2], qfB[2];
    {
        const u16* qA = QKV + (bS + qA0 + w16 + l15) * 3072 + h * 64 + quad * 8;
        qfA[0] = ldfrag(qA); qfA[1] = ldfrag(qA + 32);
        const u16* qB = QKV + (bS + qB0 + w16 + l15) * 3072 + h * 64 + quad * 8;
        qfB[0] = ldfrag(qB); qfB[1] = ldfrag(qB + 32);
    }
    float lA = 0.f, lB = 0.f;
    f32x4 OA[4], OB[4];
    const f32x4 zero = {0.f, 0.f, 0.f, 0.f};
#pragma unroll
    for (int nt = 0; nt < 4; ++nt) { OA[nt] = zero; OB[nt] = zero; }
    const f32x4 cinit = {-10.f, -10.f, -10.f, -10.f};  // folded softmax shift
    __syncthreads();  // kv block 0 staged

    for (int j = 0; j <= qbA; ++j) {
        if (j < qbA) {  // prefetch j+1; drained by end-of-iter barrier (full cover)
            const int kv1 = (j + 1) * 64;
            const int nb = (j + 1) & 1;
            const u16* ksrc = QKV + (bS + kv1 + rr) * 3072 + 1024 + h * 64 + kc8;
            async_copy16(ksrc,      Kt[nb] + tid * 8);
            async_copy16(ksrc + 32, Kt[nb] + (256 + tid) * 8);
            const u16* vsrc = vbase + (size_t)rr * 2048 + kv1 + kc8;
            async_copy16(vsrc,      Vt[nb] + tid * 8);
            async_copy16(vsrc + 32, Vt[nb] + (256 + tid) * 8);
        }
        const bool bAct = (j <= qbB);  // block-uniform
        const bool dA = (j == qbA), dB = (j == qbB);
        const u16* KB = Kt[j & 1];
        const u16* VB = Vt[j & 1];
        bf16x8 vf[4][2];
#pragma unroll
        for (int nt = 0; nt < 4; ++nt)
#pragma unroll
            for (int ks = 0; ks < 2; ++ks)
                vf[nt][ks] = ldfrag(VB + ks * 2048 + (nt * 16 + l15) * 32 + quad * 8);
        // S^T over all 4 kv-subtiles for this wave's q-rows; P stays in regs.
        u16x4 pcA[4], pcB[4];
#pragma unroll
        for (int c = 0; c < 4; ++c) {
            bf16x8 kf0 = ldfrag(KB + (c * 16 + l15) * 32 + quad * 8);
            bf16x8 kf1 = ldfrag(KB + 2048 + (c * 16 + l15) * 32 + quad * 8);
            f32x4 a = __builtin_amdgcn_mfma_f32_16x16x32_bf16(kf0, qfA[0], cinit, 0, 0, 0);
            f32x4 s = __builtin_amdgcn_mfma_f32_16x16x32_bf16(kf1, qfA[1], a, 0, 0, 0);
            if (dA) {  // mask iff local kv > local q
#pragma unroll
                for (int r = 0; r < 4; ++r)
                    if (c * 16 + quad * 4 + r > w16 + l15) s[r] = -1e30f;
            }
            u16x4 pk; float acc = 0.f;
#pragma unroll
            for (int r = 0; r < 4; ++r) {
                float pv = fexp2(s[r]);
                acc += pv;
                pk[r] = f2b(pv);
            }
            lA += acc; pcA[c] = pk;
            if (bAct) {
                f32x4 a2 = __builtin_amdgcn_mfma_f32_16x16x32_bf16(kf0, qfB[0], cinit, 0, 0, 0);
                f32x4 s2 = __builtin_amdgcn_mfma_f32_16x16x32_bf16(kf1, qfB[1], a2, 0, 0, 0);
                if (dB) {
#pragma unroll
                    for (int r = 0; r < 4; ++r)
                        if (c * 16 + quad * 4 + r > w16 + l15) s2[r] = -1e30f;
                }
                u16x4 pk2; float acc2 = 0.f;
#pragma unroll
                for (int r = 0; r < 4; ++r) {
                    float pv = fexp2(s2[r]);
                    acc2 += pv;
                    pk2[r] = f2b(pv);
                }
                lB += acc2; pcB[c] = pk2;
            }
        }
        // PV: A-frag = own registers in (c,r) order, matching sigma-permuted V.
        bf16x8 paA[2], paB[2];
#pragma unroll
        for (int ks = 0; ks < 2; ++ks) {
            u16x8 t;
#pragma unroll
            for (int i = 0; i < 4; ++i) { t[i] = pcA[2 * ks][i]; t[4 + i] = pcA[2 * ks + 1][i]; }
            paA[ks] = __builtin_bit_cast(bf16x8, t);
        }
#pragma unroll
        for (int nt = 0; nt < 4; ++nt) {
            OA[nt] = __builtin_amdgcn_mfma_f32_16x16x32_bf16(paA[0], vf[nt][0], OA[nt], 0, 0, 0);
            OA[nt] = __builtin_amdgcn_mfma_f32_16x16x32_bf16(paA[1], vf[nt][1], OA[nt], 0, 0, 0);
        }
        if (bAct) {
#pragma unroll
            for (int ks = 0; ks < 2; ++ks) {
                u16x8 t;
#pragma unroll
                for (int i = 0; i < 4; ++i) { t[i] = pcB[2 * ks][i]; t[4 + i] = pcB[2 * ks + 1][i]; }
                paB[ks] = __builtin_bit_cast(bf16x8, t);
            }
#pragma unroll
            for (int nt = 0; nt < 4; ++nt) {
                OB[nt] = __builtin_amdgcn_mfma_f32_16x16x32_bf16(paB[0], vf[nt][0], OB[nt], 0, 0, 0);
                OB[nt] = __builtin_amdgcn_mfma_f32_16x16x32_bf16(paB[1], vf[nt][1], OB[nt], 0, 0, 0);
            }
        }
        __syncthreads();  // reads done + prefetch j+1 landed
    }

    // epilogue: all-shuffle. l partial per lane; xor16+xor32 sums the quads.
    lA += __shfl_xor(lA, 16); lA += __shfl_xor(lA, 32);
    lB += __shfl_xor(lB, 16); lB += __shfl_xor(lB, 32);
#pragma unroll
    for (int r = 0; r < 4; ++r) {
        const int ql = quad * 4 + r;   // local q row of O (D layout: row=quad*4+r)
        float invA = 1.0f / __shfl(lA, ql);
        float invB = 1.0f / __shfl(lB, ql);
        size_t rowA = bS + (size_t)qA0 + w16 + ql;
        size_t rowB = bS + (size_t)qB0 + w16 + ql;
#pragma unroll
        for (int nt = 0; nt < 4; ++nt) {
            AO[rowA * 1024 + h * 64 + nt * 16 + l15] = f2b(OA[nt][r] * invA);
            AO[rowB * 1024 + h * 64 + nt * 16 + l15] = f2b(OB[nt][r] * invB);
        }
    }
}

extern "C" void kernel_launch(void* const* d_in, const int* in_sizes, int n_in,
                              void* d_out, int out_size, void* d_ws, size_t ws_size,
                              hipStream_t stream) {
    (void)in_sizes; (void)n_in; (void)out_size; (void)ws_size;
    const float* x   = (const float*)d_in[0];
    const float* Wq  = (const float*)d_in[1];
    const float* Wkv = (const float*)d_in[2];
    const float* Wo  = (const float*)d_in[3];
    float* out = (float*)d_out;
    char* ws = (char*)d_ws;
    u16* xb    = (u16*)(ws);                      // 8 MB   x bf16 [4096][1024]
    u16* WcatT = (u16*)(ws + (size_t)(8 << 20));  // 6 MB   [Wq*s | Wkv]^T  [3072][1024]
    u16* WoT   = (u16*)(ws + (size_t)(14 << 20)); // 2 MB   Wo^T [1024][1024]
    u16* QKV   = (u16*)(ws + (size_t)(16 << 20)); // 24 MB  [4096][3072] (V cols unused)
    u16* VTb   = (u16*)(ws + (size_t)(40 << 20)); // 8 MB   [32][64][2048] sigma-permuted
    u16* AO    = xb;                              // reuse: xb dead after QKV GEMM

    cast_x_kernel<<<2048, 256, 0, stream>>>(x, xb);
    transpose_all<<<dim3(16, 32, 3), 256, 0, stream>>>(Wq, Wkv, Wo, WcatT, WoT);
    gemm_bt<u16><<<768, 256, 0, stream>>>(xb, WcatT, QKV, VTb, 4096, 3072, 1024);
    attn_kernel<<<512, 256, 0, stream>>>(QKV, VTb, AO);
    gemm_bt64<<<512, 256, 0, stream>>>(AO, WoT, out, 4096, 1024, 1024);
}